// Round 1
// baseline (283.409 us; speedup 1.0000x reference)
//
#include <hip/hip_runtime.h>
#include <stdint.h>

#define EPSV 1e-7f
#define FDIM 512
#define BK 64
#define MT 128

typedef __bf16 bf16_t;
typedef bf16_t bf16x8 __attribute__((ext_vector_type(8)));
typedef unsigned short ushort8 __attribute__((ext_vector_type(8)));
typedef float f32x4 __attribute__((ext_vector_type(4)));

#define AS1 __attribute__((address_space(1)))
#define AS3 __attribute__((address_space(3)))

// RNE float -> bf16 (inputs are sane: no NaN/Inf)
__device__ __forceinline__ unsigned short f2bf(float f) {
  union { float f; unsigned int u; } c; c.f = f;
  unsigned int u = c.u;
  unsigned int r = u + 0x7fffu + ((u >> 16) & 1u);
  return (unsigned short)(r >> 16);
}

// tanh via hardware exp + rcp; clamped so e^{2x} can't overflow.
__device__ __forceinline__ float fast_tanh(float x) {
  x = fminf(15.0f, fmaxf(-15.0f, x));
  float t = __expf(2.0f * x);
  return 1.0f - 2.0f * __builtin_amdgcn_rcpf(t + 1.0f);
}

// Wt[n][k] = bf16(W[k][n])  (512x512, tiny)
__global__ void convert_W(const float* __restrict__ W, unsigned short* __restrict__ Wt) {
  int idx = blockIdx.x * 256 + threadIdx.x;
  int n = idx >> 9, k = idx & 511;
  Wt[idx] = f2bf(W[k * FDIM + n]);
}

// One block = 128 rows (all same batch b). Computes scores for its rows over
// full N=512 (4 chunks of 128), then e=exp(score), partial pooling numerator
// via global atomics, and adds its Sum(e) to sumE.
__global__ __launch_bounds__(256, 2) void gemm_fused(
    const float* __restrict__ x, const unsigned short* __restrict__ Wt,
    const float* __restrict__ bvec, const float* __restrict__ uvec,
    float* __restrict__ out, float* __restrict__ sumE) {
  __shared__ unsigned short sA[MT * BK];   // [row][64k], 16B blocks XOR-swizzled
  __shared__ unsigned short sB[MT * BK];   // [n][64k], same swizzle
  __shared__ float u_s[FDIM], b_s[FDIM];
  __shared__ float score_s[MT];
  __shared__ float e_s[MT];

  const int t = threadIdx.x;
  const int lane = t & 63;
  const int w = t >> 6;          // wave 0..3
  const int wm = w & 1;          // wave row-half
  const int wn = w >> 1;         // wave col-half
  const int quad = lane >> 4;
  const int l15 = lane & 15;
  const int m0 = blockIdx.x * MT;

  u_s[t] = uvec[t]; u_s[t + 256] = uvec[t + 256];
  b_s[t] = bvec[t]; b_s[t + 256] = bvec[t + 256];
  if (t < MT) score_s[t] = 0.0f;

  float sc[4][4];  // per-lane score partials [mi][r], summed over all n
#pragma unroll
  for (int mi = 0; mi < 4; ++mi)
#pragma unroll
    for (int r = 0; r < 4; ++r) sc[mi][r] = 0.0f;

  for (int nch = 0; nch < 4; ++nch) {
    f32x4 acc[4][4];
#pragma unroll
    for (int mi = 0; mi < 4; ++mi)
#pragma unroll
      for (int ni = 0; ni < 4; ++ni) acc[mi][ni] = (f32x4){0.f, 0.f, 0.f, 0.f};

    for (int kc = 0; kc < FDIM / BK; ++kc) {
      const int kbase = kc * BK;
      // ---- stage A: fp32 -> bf16 in VALU, 16B-swizzled ds_write_b128 ----
#pragma unroll
      for (int p = 0; p < 4; ++p) {
        int slot = t + 256 * p;        // 0..1023 16B-blocks
        int row = slot >> 3;
        int j = (slot & 7) ^ (row & 7);  // logical k-block for this phys slot
        const float* g = x + (size_t)(m0 + row) * FDIM + kbase + j * 8;
        float4 lo = *(const float4*)g;
        float4 hi = *(const float4*)(g + 4);
        ushort8 v;
        v[0] = f2bf(lo.x); v[1] = f2bf(lo.y); v[2] = f2bf(lo.z); v[3] = f2bf(lo.w);
        v[4] = f2bf(hi.x); v[5] = f2bf(hi.y); v[6] = f2bf(hi.z); v[7] = f2bf(hi.w);
        *(ushort8*)(void*)(sA + slot * 8) = v;
      }
      // ---- stage B: async global->LDS 16B, source permuted to match swizzle ----
#pragma unroll
      for (int i = 0; i < 4; ++i) {
        int nb = w * 32 + i * 8;                 // 8 rows per instruction
        int nl = nb + (lane >> 3);
        int j = (lane & 7) ^ (nl & 7);
        const unsigned short* g =
            Wt + (size_t)(nch * 128 + nl) * FDIM + kbase + j * 8;
        unsigned short* l = (unsigned short*)(sB + nb * 64);
        __builtin_amdgcn_global_load_lds((AS1 void*)(g), (AS3 void*)(l), 16, 0, 0);
      }
      __syncthreads();
      // ---- MFMA over BK=64 (2 k-steps of 32) ----
#pragma unroll
      for (int ks = 0; ks < 2; ++ks) {
        bf16x8 af[4], bfr[4];
#pragma unroll
        for (int mi = 0; mi < 4; ++mi) {
          int row = wm * 64 + mi * 16 + l15;
          int phys = (ks * 4 + quad) ^ (row & 7);
          af[mi] = *(const bf16x8*)(const void*)(sA + row * 64 + phys * 8);
        }
#pragma unroll
        for (int ni = 0; ni < 4; ++ni) {
          int row = wn * 64 + ni * 16 + l15;
          int phys = (ks * 4 + quad) ^ (row & 7);
          bfr[ni] = *(const bf16x8*)(const void*)(sB + row * 64 + phys * 8);
        }
#pragma unroll
        for (int mi = 0; mi < 4; ++mi)
#pragma unroll
          for (int ni = 0; ni < 4; ++ni)
            acc[mi][ni] = __builtin_amdgcn_mfma_f32_16x16x32_bf16(
                af[mi], bfr[ni], acc[mi][ni], 0, 0, 0);
      }
      __syncthreads();
    }
    // ---- epilogue for this n-chunk: sc += u * tanh(C + b) ----
#pragma unroll
    for (int ni = 0; ni < 4; ++ni) {
      int col = nch * 128 + wn * 64 + ni * 16 + l15;
      float uu = u_s[col], bb = b_s[col];
#pragma unroll
      for (int mi = 0; mi < 4; ++mi)
#pragma unroll
        for (int r = 0; r < 4; ++r)
          sc[mi][r] += uu * fast_tanh(acc[mi][ni][r] + bb);
    }
  }

  // ---- reduce score partials across the 16 col-lanes, into LDS ----
#pragma unroll
  for (int mi = 0; mi < 4; ++mi)
#pragma unroll
    for (int r = 0; r < 4; ++r) {
      float v = sc[mi][r];
      v += __shfl_xor(v, 1); v += __shfl_xor(v, 2);
      v += __shfl_xor(v, 4); v += __shfl_xor(v, 8);
      if (l15 == 0)
        atomicAdd(&score_s[wm * 64 + mi * 16 + quad * 4 + r], v);
    }
  __syncthreads();

  if (t < MT) e_s[t] = __expf(score_s[t]);
  __syncthreads();

  if (t < 64) {
    float s = e_s[t] + e_s[t + 64];
    s += __shfl_xor(s, 1);  s += __shfl_xor(s, 2);  s += __shfl_xor(s, 4);
    s += __shfl_xor(s, 8);  s += __shfl_xor(s, 16); s += __shfl_xor(s, 32);
    if (t == 0) atomicAdd(sumE, s);
  }

  // ---- pooling numerator: out[b,f] += sum_rows x[row,f] * e[row] ----
  const int half = t >> 7;     // rows 0..63 / 64..127
  const int f4 = t & 127;      // float4 index over F=512
  float ax = 0.f, ay = 0.f, az = 0.f, aw = 0.f;
  for (int r = 0; r < 64; ++r) {
    int row = half * 64 + r;
    const float4 xv = *(const float4*)(x + (size_t)(m0 + row) * FDIM + f4 * 4);
    float wgt = e_s[row];
    ax += xv.x * wgt; ay += xv.y * wgt; az += xv.z * wgt; aw += xv.w * wgt;
  }
  const int bidx = m0 >> 12;   // 4096 rows per batch
  float* op = out + bidx * FDIM + f4 * 4;
  atomicAdd(op + 0, ax); atomicAdd(op + 1, ay);
  atomicAdd(op + 2, az); atomicAdd(op + 3, aw);
}

__global__ void normalize_k(float* __restrict__ out, const float* __restrict__ sumE) {
  int i = blockIdx.x * 256 + threadIdx.x;
  out[i] *= 1.0f / (*sumE + EPSV);
}

extern "C" void kernel_launch(void* const* d_in, const int* in_sizes, int n_in,
                              void* d_out, int out_size, void* d_ws, size_t ws_size,
                              hipStream_t stream) {
  (void)in_sizes; (void)n_in; (void)ws_size;
  const float* x = (const float*)d_in[0];
  const float* W = (const float*)d_in[1];
  const float* b = (const float*)d_in[2];
  const float* u = (const float*)d_in[3];
  float* out = (float*)d_out;

  unsigned short* Wt = (unsigned short*)d_ws;                       // 512 KB
  float* sumE = (float*)((char*)d_ws + FDIM * FDIM * sizeof(unsigned short));

  hipMemsetAsync(d_out, 0, (size_t)out_size * sizeof(float), stream);
  hipMemsetAsync(sumE, 0, sizeof(float), stream);

  convert_W<<<dim3(FDIM * FDIM / 256), dim3(256), 0, stream>>>(W, Wt);
  gemm_fused<<<dim3(65536 / MT), dim3(256), 0, stream>>>(x, Wt, b, u, out, sumE);
  normalize_k<<<dim3(16 * FDIM / 256), dim3(256), 0, stream>>>(out, sumE);
}

// Round 2
// 277.021 us; speedup vs baseline: 1.0231x; 1.0231x over previous
//
#include <hip/hip_runtime.h>
#include <stdint.h>

#define EPSV 1e-7f
#define FDIM 512
#define BK 64
#define NROWS 65536   // 16*4096

typedef __bf16 bf16_t;
typedef bf16_t bf16x8 __attribute__((ext_vector_type(8)));
typedef unsigned short ushort8 __attribute__((ext_vector_type(8)));
typedef float f32x4 __attribute__((ext_vector_type(4)));

#define AS1 __attribute__((address_space(1)))
#define AS3 __attribute__((address_space(3)))

// RNE float -> bf16
__device__ __forceinline__ unsigned short f2bf(float f) {
  union { float f; unsigned int u; } c; c.f = f;
  unsigned int u = c.u;
  unsigned int r = u + 0x7fffu + ((u >> 16) & 1u);
  return (unsigned short)(r >> 16);
}

// tanh via hardware exp + rcp; clamped so e^{2x} can't overflow.
__device__ __forceinline__ float fast_tanh(float x) {
  x = fminf(15.0f, fmaxf(-15.0f, x));
  float t = __expf(2.0f * x);
  return 1.0f - 2.0f * __builtin_amdgcn_rcpf(t + 1.0f);
}

// Wt[n][k] = bf16(W[k][n]) via LDS tile transpose, both sides coalesced.
__global__ void convert_W(const float* __restrict__ W, unsigned short* __restrict__ Wt) {
  __shared__ unsigned short tile[32][34];
  const int t = threadIdx.x;
  const int tx = t & 31, ty = t >> 5;                  // ty 0..7
  const int bn = blockIdx.x & 15, bk = blockIdx.x >> 4;
  const int k0 = bk * 32, n0 = bn * 32;
#pragma unroll
  for (int i = 0; i < 4; ++i) {
    int r = ty + i * 8;
    tile[r][tx] = f2bf(W[(size_t)(k0 + r) * FDIM + n0 + tx]);
  }
  __syncthreads();
#pragma unroll
  for (int i = 0; i < 4; ++i) {
    int r = ty + i * 8;
    Wt[(size_t)(n0 + r) * FDIM + k0 + tx] = tile[tx][r];
  }
}

// One block = 128 rows x 128 cols (one n-chunk). Writes per-chunk score
// partials (no atomics): spart[nch*65536 + row].
__global__ __launch_bounds__(256, 4) void gemm_score(
    const float* __restrict__ x, const unsigned short* __restrict__ Wt,
    const float* __restrict__ bvec, const float* __restrict__ uvec,
    float* __restrict__ spart) {
  __shared__ unsigned short sA[128 * BK];   // [row][64k], 16B blocks XOR-swizzled
  __shared__ unsigned short sB[128 * BK];   // [n][64k], same swizzle
  __shared__ float score_s[128];
  __shared__ float ub_s[128], bb_s[128];

  const int t = threadIdx.x;
  const int lane = t & 63;
  const int w = t >> 6;          // wave 0..3
  const int wm = w & 1;          // wave row-half
  const int wn = w >> 1;         // wave col-half
  const int quad = lane >> 4;
  const int l15 = lane & 15;
  const int rt = blockIdx.x >> 2;
  const int nch = blockIdx.x & 3;
  const int m0 = rt * 128;
  const int col0 = nch * 128;

  if (t < 128) {
    score_s[t] = 0.0f;
    ub_s[t] = uvec[col0 + t];
    bb_s[t] = bvec[col0 + t];
  }

  f32x4 acc[4][4];
#pragma unroll
  for (int mi = 0; mi < 4; ++mi)
#pragma unroll
    for (int ni = 0; ni < 4; ++ni) acc[mi][ni] = (f32x4){0.f, 0.f, 0.f, 0.f};

  for (int kc = 0; kc < FDIM / BK; ++kc) {
    const int kbase = kc * BK;
    // ---- stage A: fp32 -> bf16 in VALU, 16B-swizzled ds_write_b128 ----
#pragma unroll
    for (int p = 0; p < 4; ++p) {
      int slot = t + 256 * p;          // 0..1023 16B-blocks
      int row = slot >> 3;
      int j = (slot & 7) ^ (row & 7);  // logical k-block for this phys slot
      const float* g = x + (size_t)(m0 + row) * FDIM + kbase + j * 8;
      float4 lo = *(const float4*)g;
      float4 hi = *(const float4*)(g + 4);
      ushort8 v;
      v[0] = f2bf(lo.x); v[1] = f2bf(lo.y); v[2] = f2bf(lo.z); v[3] = f2bf(lo.w);
      v[4] = f2bf(hi.x); v[5] = f2bf(hi.y); v[6] = f2bf(hi.z); v[7] = f2bf(hi.w);
      *(ushort8*)(void*)(sA + slot * 8) = v;
    }
    // ---- stage B: async global->LDS 16B, source permuted to match swizzle ----
#pragma unroll
    for (int i = 0; i < 4; ++i) {
      int nb = w * 32 + i * 8;                 // 8 rows per instruction
      int nl = nb + (lane >> 3);
      int j = (lane & 7) ^ (nl & 7);
      const unsigned short* g =
          Wt + (size_t)(col0 + nl) * FDIM + kbase + j * 8;
      unsigned short* l = (unsigned short*)(sB + nb * 64);
      __builtin_amdgcn_global_load_lds((AS1 void*)(g), (AS3 void*)(l), 16, 0, 0);
    }
    __syncthreads();
    // ---- MFMA over BK=64 (2 k-steps of 32) ----
#pragma unroll
    for (int ks = 0; ks < 2; ++ks) {
      bf16x8 af[4], bfr[4];
#pragma unroll
      for (int mi = 0; mi < 4; ++mi) {
        int row = wm * 64 + mi * 16 + l15;
        int phys = (ks * 4 + quad) ^ (row & 7);
        af[mi] = *(const bf16x8*)(const void*)(sA + row * 64 + phys * 8);
      }
#pragma unroll
      for (int ni = 0; ni < 4; ++ni) {
        int row = wn * 64 + ni * 16 + l15;
        int phys = (ks * 4 + quad) ^ (row & 7);
        bfr[ni] = *(const bf16x8*)(const void*)(sB + row * 64 + phys * 8);
      }
#pragma unroll
      for (int mi = 0; mi < 4; ++mi)
#pragma unroll
        for (int ni = 0; ni < 4; ++ni)
          acc[mi][ni] = __builtin_amdgcn_mfma_f32_16x16x32_bf16(
              af[mi], bfr[ni], acc[mi][ni], 0, 0, 0);
    }
    __syncthreads();
  }

  // ---- epilogue: sc = sum_n u[n] * tanh(C + b[n]) over this chunk ----
  float sc[4][4];
#pragma unroll
  for (int mi = 0; mi < 4; ++mi)
#pragma unroll
    for (int r = 0; r < 4; ++r) sc[mi][r] = 0.0f;
#pragma unroll
  for (int ni = 0; ni < 4; ++ni) {
    int cl = wn * 64 + ni * 16 + l15;
    float uu = ub_s[cl], bb = bb_s[cl];
#pragma unroll
    for (int mi = 0; mi < 4; ++mi)
#pragma unroll
      for (int r = 0; r < 4; ++r)
        sc[mi][r] += uu * fast_tanh(acc[mi][ni][r] + bb);
  }
  // reduce across the 16 col-lanes; combine the two wn waves via LDS atomics
#pragma unroll
  for (int mi = 0; mi < 4; ++mi)
#pragma unroll
    for (int r = 0; r < 4; ++r) {
      float v = sc[mi][r];
      v += __shfl_xor(v, 1); v += __shfl_xor(v, 2);
      v += __shfl_xor(v, 4); v += __shfl_xor(v, 8);
      if (l15 == 0)
        atomicAdd(&score_s[wm * 64 + mi * 16 + quad * 4 + r], v);
    }
  __syncthreads();
  if (t < 128) spart[(size_t)nch * NROWS + m0 + t] = score_s[t];
}

// score = sum of 4 chunk partials; e = exp(score) written in-place over
// spart row 0; block-reduced Sum(e) -> sumE.
__global__ void score_exp(float* __restrict__ spart, float* __restrict__ sumE) {
  __shared__ float ws_[4];
  const int t = threadIdx.x;
  const int i = blockIdx.x * 256 + t;
  float s = spart[i] + spart[i + NROWS] + spart[i + 2 * NROWS] + spart[i + 3 * NROWS];
  float e = __expf(s);
  spart[i] = e;
  float v = e;
  v += __shfl_xor(v, 1);  v += __shfl_xor(v, 2);  v += __shfl_xor(v, 4);
  v += __shfl_xor(v, 8);  v += __shfl_xor(v, 16); v += __shfl_xor(v, 32);
  if ((t & 63) == 0) ws_[t >> 6] = v;
  __syncthreads();
  if (t == 0) atomicAdd(sumE, ws_[0] + ws_[1] + ws_[2] + ws_[3]);
}

// out[b,f] += sum_rows x[row,f] * e[row] / (sumE+eps); 128 rows per block.
__global__ __launch_bounds__(256) void pool_k(
    const float* __restrict__ x, const float* __restrict__ e,
    const float* __restrict__ sumE, float* __restrict__ out) {
  __shared__ float e_s[128];
  __shared__ float4 red[128];
  const int t = threadIdx.x;
  const int b = blockIdx.x >> 5, chunk = blockIdx.x & 31;
  const int g0 = b * 4096 + chunk * 128;
  if (t < 128) e_s[t] = e[g0 + t];
  __syncthreads();
  const int parity = t >> 7, f4 = t & 127;
  float ax = 0.f, ay = 0.f, az = 0.f, aw = 0.f;
  for (int r = 0; r < 64; ++r) {
    int row = r * 2 + parity;
    const float4 xv = *(const float4*)(x + (size_t)(g0 + row) * FDIM + f4 * 4);
    float wgt = e_s[row];
    ax += xv.x * wgt; ay += xv.y * wgt; az += xv.z * wgt; aw += xv.w * wgt;
  }
  if (parity) red[f4] = (float4){ax, ay, az, aw};
  __syncthreads();
  if (!parity) {
    float4 o = red[f4];
    float inv = 1.0f / (*sumE + EPSV);
    float* op = out + (size_t)b * FDIM + f4 * 4;
    atomicAdd(op + 0, (ax + o.x) * inv);
    atomicAdd(op + 1, (ay + o.y) * inv);
    atomicAdd(op + 2, (az + o.z) * inv);
    atomicAdd(op + 3, (aw + o.w) * inv);
  }
}

extern "C" void kernel_launch(void* const* d_in, const int* in_sizes, int n_in,
                              void* d_out, int out_size, void* d_ws, size_t ws_size,
                              hipStream_t stream) {
  (void)in_sizes; (void)n_in; (void)ws_size;
  const float* x = (const float*)d_in[0];
  const float* W = (const float*)d_in[1];
  const float* b = (const float*)d_in[2];
  const float* u = (const float*)d_in[3];
  float* out = (float*)d_out;

  // ws layout: Wt (512 KB) | spart[4][65536] (1 MB, row 0 reused as e) | sumE
  unsigned short* Wt = (unsigned short*)d_ws;
  float* spart = (float*)((char*)d_ws + (size_t)FDIM * FDIM * sizeof(unsigned short));
  float* sumE = spart + 4 * NROWS;

  hipMemsetAsync(d_out, 0, (size_t)out_size * sizeof(float), stream);
  hipMemsetAsync(sumE, 0, sizeof(float), stream);

  convert_W<<<dim3(256), dim3(256), 0, stream>>>(W, Wt);
  gemm_score<<<dim3(2048), dim3(256), 0, stream>>>(x, Wt, b, u, spart);
  score_exp<<<dim3(NROWS / 256), dim3(256), 0, stream>>>(spart, sumE);
  pool_k<<<dim3(512), dim3(256), 0, stream>>>(x, spart, sumE, out);
}

// Round 3
// 274.605 us; speedup vs baseline: 1.0321x; 1.0088x over previous
//
#include <hip/hip_runtime.h>
#include <stdint.h>

#define EPSV 1e-7f
#define FDIM 512
#define BK 64
#define NROWS 65536   // 16*4096

typedef __bf16 bf16_t;
typedef bf16_t bf16x8 __attribute__((ext_vector_type(8)));
typedef unsigned short ushort8 __attribute__((ext_vector_type(8)));
typedef float f32x4 __attribute__((ext_vector_type(4)));

#define AS1 __attribute__((address_space(1)))
#define AS3 __attribute__((address_space(3)))

// RNE float -> bf16
__device__ __forceinline__ unsigned short f2bf(float f) {
  union { float f; unsigned int u; } c; c.f = f;
  unsigned int u = c.u;
  unsigned int r = u + 0x7fffu + ((u >> 16) & 1u);
  return (unsigned short)(r >> 16);
}
__device__ __forceinline__ float bf2f(unsigned short s) {
  union { unsigned int u; float f; } c; c.u = ((unsigned int)s) << 16;
  return c.f;
}

// tanh via hardware exp + rcp; clamped so e^{2x} can't overflow.
__device__ __forceinline__ float fast_tanh(float x) {
  x = fminf(15.0f, fmaxf(-15.0f, x));
  float t = __expf(2.0f * x);
  return 1.0f - 2.0f * __builtin_amdgcn_rcpf(t + 1.0f);
}

// Wt[n][k] = bf16(W[k][n]) via LDS tile transpose, both sides coalesced.
__global__ void convert_W(const float* __restrict__ W, unsigned short* __restrict__ Wt) {
  __shared__ unsigned short tile[32][34];
  const int t = threadIdx.x;
  const int tx = t & 31, ty = t >> 5;
  const int bn = blockIdx.x & 15, bk = blockIdx.x >> 4;
  const int k0 = bk * 32, n0 = bn * 32;
#pragma unroll
  for (int i = 0; i < 4; ++i) {
    int r = ty + i * 8;
    tile[r][tx] = f2bf(W[(size_t)(k0 + r) * FDIM + n0 + tx]);
  }
  __syncthreads();
#pragma unroll
  for (int i = 0; i < 4; ++i) {
    int r = ty + i * 8;
    Wt[(size_t)(n0 + r) * FDIM + k0 + tx] = tile[tx][r];
  }
}

// x fp32 -> bf16, pure streaming (8 elements/thread)
__global__ __launch_bounds__(256) void convert_x(const float* __restrict__ x,
                                                 unsigned short* __restrict__ xbf) {
  size_t i = ((size_t)blockIdx.x * 256 + threadIdx.x) * 8;
  float4 lo = *(const float4*)(x + i);
  float4 hi = *(const float4*)(x + i + 4);
  ushort8 v;
  v[0] = f2bf(lo.x); v[1] = f2bf(lo.y); v[2] = f2bf(lo.z); v[3] = f2bf(lo.w);
  v[4] = f2bf(hi.x); v[5] = f2bf(hi.y); v[6] = f2bf(hi.z); v[7] = f2bf(hi.w);
  *(ushort8*)(xbf + i) = v;
}

// One block = 128 rows x 128 cols (one n-chunk). nch = high grid bits so the
// 4 column passes are temporal (L3 reuse of A). Writes per-chunk score
// partials: spart[nch*65536 + row].
template <bool ABF>
__global__ __launch_bounds__(256, 4) void gemm_score(
    const float* __restrict__ x, const unsigned short* __restrict__ xbf,
    const unsigned short* __restrict__ Wt,
    const float* __restrict__ bvec, const float* __restrict__ uvec,
    float* __restrict__ spart) {
  __shared__ unsigned short sA[128 * BK];   // [row][64k], 16B blocks XOR-swizzled
  __shared__ unsigned short sB[128 * BK];   // [n][64k], same swizzle
  __shared__ float score_s[128];
  __shared__ float ub_s[128], bb_s[128];

  const int t = threadIdx.x;
  const int lane = t & 63;
  const int w = t >> 6;
  const int wm = w & 1;
  const int wn = w >> 1;
  const int quad = lane >> 4;
  const int l15 = lane & 15;
  const int nch = blockIdx.x >> 9;       // temporal passes
  const int rt = blockIdx.x & 511;
  const int m0 = rt * 128;
  const int col0 = nch * 128;

  if (t < 128) {
    score_s[t] = 0.0f;
    ub_s[t] = uvec[col0 + t];
    bb_s[t] = bvec[col0 + t];
  }

  f32x4 acc[4][4];
#pragma unroll
  for (int mi = 0; mi < 4; ++mi)
#pragma unroll
    for (int ni = 0; ni < 4; ++ni) acc[mi][ni] = (f32x4){0.f, 0.f, 0.f, 0.f};

  for (int kc = 0; kc < FDIM / BK; ++kc) {
    const int kbase = kc * BK;
    if constexpr (ABF) {
      // ---- stage A: async global->LDS 16B from bf16 x, swizzled source ----
#pragma unroll
      for (int i = 0; i < 4; ++i) {
        int rb = w * 32 + i * 8;
        int rl = rb + (lane >> 3);
        int j = (lane & 7) ^ (rl & 7);
        const unsigned short* g =
            xbf + (size_t)(m0 + rl) * FDIM + kbase + j * 8;
        unsigned short* l = (unsigned short*)(sA + rb * 64);
        __builtin_amdgcn_global_load_lds((AS1 void*)(g), (AS3 void*)(l), 16, 0, 0);
      }
    } else {
      // ---- stage A: fp32 -> bf16 in VALU, swizzled ds_write_b128 ----
#pragma unroll
      for (int p = 0; p < 4; ++p) {
        int slot = t + 256 * p;
        int row = slot >> 3;
        int j = (slot & 7) ^ (row & 7);
        const float* g = x + (size_t)(m0 + row) * FDIM + kbase + j * 8;
        float4 lo = *(const float4*)g;
        float4 hi = *(const float4*)(g + 4);
        ushort8 v;
        v[0] = f2bf(lo.x); v[1] = f2bf(lo.y); v[2] = f2bf(lo.z); v[3] = f2bf(lo.w);
        v[4] = f2bf(hi.x); v[5] = f2bf(hi.y); v[6] = f2bf(hi.z); v[7] = f2bf(hi.w);
        *(ushort8*)(void*)(sA + slot * 8) = v;
      }
    }
    // ---- stage B: async global->LDS 16B, swizzled source ----
#pragma unroll
    for (int i = 0; i < 4; ++i) {
      int nb = w * 32 + i * 8;
      int nl = nb + (lane >> 3);
      int j = (lane & 7) ^ (nl & 7);
      const unsigned short* g =
          Wt + (size_t)(col0 + nl) * FDIM + kbase + j * 8;
      unsigned short* l = (unsigned short*)(sB + nb * 64);
      __builtin_amdgcn_global_load_lds((AS1 void*)(g), (AS3 void*)(l), 16, 0, 0);
    }
    __syncthreads();
    // ---- MFMA over BK=64 (2 k-steps of 32) ----
#pragma unroll
    for (int ks = 0; ks < 2; ++ks) {
      bf16x8 af[4], bfr[4];
#pragma unroll
      for (int mi = 0; mi < 4; ++mi) {
        int row = wm * 64 + mi * 16 + l15;
        int phys = (ks * 4 + quad) ^ (row & 7);
        af[mi] = *(const bf16x8*)(const void*)(sA + row * 64 + phys * 8);
      }
#pragma unroll
      for (int ni = 0; ni < 4; ++ni) {
        int row = wn * 64 + ni * 16 + l15;
        int phys = (ks * 4 + quad) ^ (row & 7);
        bfr[ni] = *(const bf16x8*)(const void*)(sB + row * 64 + phys * 8);
      }
#pragma unroll
      for (int mi = 0; mi < 4; ++mi)
#pragma unroll
        for (int ni = 0; ni < 4; ++ni)
          acc[mi][ni] = __builtin_amdgcn_mfma_f32_16x16x32_bf16(
              af[mi], bfr[ni], acc[mi][ni], 0, 0, 0);
    }
    __syncthreads();
  }

  // ---- epilogue: sc = sum_n u[n] * tanh(C + b[n]) over this chunk ----
  float sc[4][4];
#pragma unroll
  for (int mi = 0; mi < 4; ++mi)
#pragma unroll
    for (int r = 0; r < 4; ++r) sc[mi][r] = 0.0f;
#pragma unroll
  for (int ni = 0; ni < 4; ++ni) {
    int cl = wn * 64 + ni * 16 + l15;
    float uu = ub_s[cl], bb = bb_s[cl];
#pragma unroll
    for (int mi = 0; mi < 4; ++mi)
#pragma unroll
      for (int r = 0; r < 4; ++r)
        sc[mi][r] += uu * fast_tanh(acc[mi][ni][r] + bb);
  }
#pragma unroll
  for (int mi = 0; mi < 4; ++mi)
#pragma unroll
    for (int r = 0; r < 4; ++r) {
      float v = sc[mi][r];
      v += __shfl_xor(v, 1); v += __shfl_xor(v, 2);
      v += __shfl_xor(v, 4); v += __shfl_xor(v, 8);
      if (l15 == 0)
        atomicAdd(&score_s[wm * 64 + mi * 16 + quad * 4 + r], v);
    }
  __syncthreads();
  if (t < 128) spart[(size_t)nch * NROWS + m0 + t] = score_s[t];
}

// score = sum of 4 chunk partials; e = exp(score) in-place over row 0;
// block-reduced Sum(e) -> sumE.
__global__ void score_exp(float* __restrict__ spart, float* __restrict__ sumE) {
  __shared__ float ws_[4];
  const int t = threadIdx.x;
  const int i = blockIdx.x * 256 + t;
  float s = spart[i] + spart[i + NROWS] + spart[i + 2 * NROWS] + spart[i + 3 * NROWS];
  float e = __expf(s);
  spart[i] = e;
  float v = e;
  v += __shfl_xor(v, 1);  v += __shfl_xor(v, 2);  v += __shfl_xor(v, 4);
  v += __shfl_xor(v, 8);  v += __shfl_xor(v, 16); v += __shfl_xor(v, 32);
  if ((t & 63) == 0) ws_[t >> 6] = v;
  __syncthreads();
  if (t == 0) atomicAdd(sumE, ws_[0] + ws_[1] + ws_[2] + ws_[3]);
}

// --- primary pooling: 32 rows/block from xbf, atomic-free partials ---
__global__ __launch_bounds__(256, 8) void pool_part(
    const unsigned short* __restrict__ xbf, const float* __restrict__ e,
    float* __restrict__ ppool) {
  __shared__ float e_s[32];
  __shared__ float red[4][FDIM];
  const int t = threadIdx.x;
  const int c8 = t & 63, rg = t >> 6;
  const int r0 = blockIdx.x * 32;
  if (t < 32) e_s[t] = e[r0 + t];
  __syncthreads();
  float a[8];
#pragma unroll
  for (int j = 0; j < 8; ++j) a[j] = 0.0f;
  for (int it = 0; it < 8; ++it) {
    int row = rg * 8 + it;
    ushort8 v = *(const ushort8*)(xbf + (size_t)(r0 + row) * FDIM + c8 * 8);
    float wg = e_s[row];
#pragma unroll
    for (int j = 0; j < 8; ++j) a[j] += bf2f(v[j]) * wg;
  }
  *(float4*)&red[rg][c8 * 8]     = (float4){a[0], a[1], a[2], a[3]};
  *(float4*)&red[rg][c8 * 8 + 4] = (float4){a[4], a[5], a[6], a[7]};
  __syncthreads();
  int c = t, c2 = t + 256;
  float s0 = red[0][c] + red[1][c] + red[2][c] + red[3][c];
  float s1 = red[0][c2] + red[1][c2] + red[2][c2] + red[3][c2];
  ppool[(size_t)blockIdx.x * FDIM + c]  = s0;
  ppool[(size_t)blockIdx.x * FDIM + c2] = s1;
}

// out[b,f] = inv * sum over the 128 chunk-partials of batch b.
__global__ __launch_bounds__(256) void pool_reduce(
    const float* __restrict__ ppool, const float* __restrict__ sumE,
    float* __restrict__ out) {
  const int i = blockIdx.x * 256 + threadIdx.x;   // 0..8191
  const int b = i >> 9, f = i & 511;
  float s = 0.0f;
  const float* p = ppool + (size_t)b * 128 * FDIM + f;
  for (int c = 0; c < 128; ++c) s += p[(size_t)c * FDIM];
  out[i] = s / (*sumE + EPSV);
}

// --- fallback pooling (fp32 x, atomics), proven in round 2 ---
__global__ __launch_bounds__(256) void pool_k(
    const float* __restrict__ x, const float* __restrict__ e,
    const float* __restrict__ sumE, float* __restrict__ out) {
  __shared__ float e_s[128];
  __shared__ float4 red[128];
  const int t = threadIdx.x;
  const int b = blockIdx.x >> 5, chunk = blockIdx.x & 31;
  const int g0 = b * 4096 + chunk * 128;
  if (t < 128) e_s[t] = e[g0 + t];
  __syncthreads();
  const int parity = t >> 7, f4 = t & 127;
  float ax = 0.f, ay = 0.f, az = 0.f, aw = 0.f;
  for (int r = 0; r < 64; ++r) {
    int row = r * 2 + parity;
    const float4 xv = *(const float4*)(x + (size_t)(g0 + row) * FDIM + f4 * 4);
    float wgt = e_s[row];
    ax += xv.x * wgt; ay += xv.y * wgt; az += xv.z * wgt; aw += xv.w * wgt;
  }
  if (parity) red[f4] = (float4){ax, ay, az, aw};
  __syncthreads();
  if (!parity) {
    float4 o = red[f4];
    float inv = 1.0f / (*sumE + EPSV);
    float* op = out + (size_t)b * FDIM + f4 * 4;
    atomicAdd(op + 0, (ax + o.x) * inv);
    atomicAdd(op + 1, (ay + o.y) * inv);
    atomicAdd(op + 2, (az + o.z) * inv);
    atomicAdd(op + 3, (aw + o.w) * inv);
  }
}

extern "C" void kernel_launch(void* const* d_in, const int* in_sizes, int n_in,
                              void* d_out, int out_size, void* d_ws, size_t ws_size,
                              hipStream_t stream) {
  (void)in_sizes; (void)n_in;
  const float* x = (const float*)d_in[0];
  const float* W = (const float*)d_in[1];
  const float* b = (const float*)d_in[2];
  const float* u = (const float*)d_in[3];
  float* out = (float*)d_out;

  // ws layout: Wt 512K | spart 1M | sumE (pad 256) | ppool 4M | xbf 64M
  char* p = (char*)d_ws;
  unsigned short* Wt = (unsigned short*)p;            p += (size_t)FDIM * FDIM * 2;
  float* spart = (float*)p;                           p += (size_t)4 * NROWS * 4;
  float* sumE = (float*)p;                            p += 256;
  float* ppool = (float*)p;                           p += (size_t)2048 * FDIM * 4;
  unsigned short* xbf = (unsigned short*)p;           p += (size_t)NROWS * FDIM * 2;
  const size_t need = (size_t)(p - (char*)d_ws);
  const bool big = ws_size >= need;

  hipMemsetAsync(sumE, 0, sizeof(float), stream);
  convert_W<<<dim3(256), dim3(256), 0, stream>>>(W, Wt);

  if (big) {
    convert_x<<<dim3(NROWS * FDIM / (256 * 8)), dim3(256), 0, stream>>>(x, xbf);
    gemm_score<true><<<dim3(2048), dim3(256), 0, stream>>>(x, xbf, Wt, b, u, spart);
    score_exp<<<dim3(NROWS / 256), dim3(256), 0, stream>>>(spart, sumE);
    pool_part<<<dim3(2048), dim3(256), 0, stream>>>(xbf, spart, ppool);
    pool_reduce<<<dim3(32), dim3(256), 0, stream>>>(ppool, sumE, out);
  } else {
    hipMemsetAsync(d_out, 0, (size_t)out_size * sizeof(float), stream);
    gemm_score<false><<<dim3(2048), dim3(256), 0, stream>>>(x, xbf, Wt, b, u, spart);
    score_exp<<<dim3(NROWS / 256), dim3(256), 0, stream>>>(spart, sumE);
    pool_k<<<dim3(512), dim3(256), 0, stream>>>(x, spart, sumE, out);
  }
}